// Round 12
// baseline (1484.092 us; speedup 1.0000x reference)
//
#include <hip/hip_runtime.h>

#define NSEG 8
#define SEGSH 19 // edge-index segment for deg8 counters
#define NGRP 8   // dst-range groups; group = blockIdx%8 -> fixed XCD
#define CHUNK 2048
#define CSTR 64  // colsum element stride (256B) -> spread across L2 slices
#define SEGP 8   // node-index segments for degree histogram (cuts same-address atomics)

typedef float    f2 __attribute__((ext_vector_type(2)));
typedef float    f4 __attribute__((ext_vector_type(4)));
typedef float    f8 __attribute__((ext_vector_type(8)));
typedef _Float16 h8 __attribute__((ext_vector_type(8)));

__device__ __forceinline__ unsigned f2key(float x){
  unsigned b = __float_as_uint(x);
  return (b & 0x80000000u) ? ~b : (b | 0x80000000u);
}
__device__ __forceinline__ float key2f(unsigned k){
  return (k & 0x80000000u) ? __uint_as_float(k ^ 0x80000000u) : __uint_as_float(~k);
}

// fp8 e4m3 HW decode
__device__ __forceinline__ f4 dec4(unsigned w){
  f2 a = __builtin_amdgcn_cvt_pk_f32_fp8((int)w, false);
  f2 b = __builtin_amdgcn_cvt_pk_f32_fp8((int)w, true);
  f4 r; r[0]=a[0]; r[1]=a[1]; r[2]=b[0]; r[3]=b[1];
  return r;
}
__device__ __forceinline__ f8 dec8(uint2 w){
  f4 lo = dec4(w.x), hi = dec4(w.y);
  f8 r;
  r[0]=lo[0]; r[1]=lo[1]; r[2]=lo[2]; r[3]=lo[3];
  r[4]=hi[0]; r[5]=hi[1]; r[6]=hi[2]; r[7]=hi[3];
  return r;
}

// ---------------- CSR build ----------------
// k_deg now dst-range-grouped like k_fill: counter atomics stay in one XCD's L2.

__global__ __launch_bounds__(256) void k_deg(const int* __restrict__ ei, int* __restrict__ deg8, int E, int n){
  int g = blockIdx.x & (NGRP-1);
  int j = blockIdx.x >> 3;
  int span = (n + NGRP - 1) / NGRP;
  int lo = g * span;
  int base = j * CHUNK;
  if (base >= E) return;
  int end = base + CHUNK; if (end > E) end = E;
  for (int e = base + threadIdx.x; e < end; e += 256){
    int d = ei[E + e];
    if ((unsigned)(d - lo) < (unsigned)span && (unsigned)d < (unsigned)n){
      int seg = e >> SEGSH; if (seg > NSEG-1) seg = NSEG-1;
      atomicAdd(&deg8[seg*n + d], 1);
    }
  }
}

__global__ __launch_bounds__(1024) void k_scan1(const int* __restrict__ deg8, int* __restrict__ offs,
                                                int* __restrict__ bsum, int n){
  __shared__ int tmp[1024];
  int tid = threadIdx.x;
  int gid = blockIdx.x*1024 + tid;
  int v = 0;
  if (gid < n){
    #pragma unroll
    for (int s=0;s<NSEG;s++) v += deg8[s*n + gid];
  }
  tmp[tid] = v;
  __syncthreads();
  for (int o=1;o<1024;o<<=1){
    int t = (tid>=o) ? tmp[tid-o] : 0;
    __syncthreads();
    if (tid>=o) tmp[tid] += t;
    __syncthreads();
  }
  int inc = tmp[tid];
  if (gid < n) offs[gid] = inc - v;   // exclusive within chunk
  if (tid == 1023) bsum[blockIdx.x] = inc;
}

__global__ void k_scan2(const int* __restrict__ bsum, int* __restrict__ bpre, int nb){
  if (threadIdx.x==0 && blockIdx.x==0){
    int acc=0;
    for (int i=0;i<nb;i++){ bpre[i]=acc; acc+=bsum[i]; }
  }
}

__global__ void k_scan3(int* __restrict__ offs, const int* __restrict__ bpre,
                        const int* __restrict__ deg8, int* __restrict__ cursor,
                        float* __restrict__ invdeg, int* __restrict__ degv,
                        int* __restrict__ hist8, int n, int E){
  int gid = blockIdx.x*blockDim.x + threadIdx.x;
  if (gid < n){
    int base = offs[gid] + bpre[gid>>10];
    offs[gid] = base;
    cursor[gid] = base;
    int dtot = 0;
    #pragma unroll
    for (int s=0;s<NSEG;s++) dtot += deg8[s*n + gid];
    invdeg[gid] = (dtot>0) ? 1.0f/(float)dtot : 0.0f;  // 0 marks isolated node (ref avg = 0)
    degv[gid] = dtot;
    int b = dtot > 255 ? 255 : dtot;
    atomicAdd(&hist8[b*SEGP + (gid>>14)], 1);
  }
  if (gid==0) offs[n] = E;
}

// exclusive scan of hist8[256*SEGP] (bucket-major) -> hcur8 (scatter cursors)
__global__ __launch_bounds__(256) void k_hscan(const int* __restrict__ hist8, int* __restrict__ hcur8){
  __shared__ int tsum[256];
  int tid = threadIdx.x;
  int loc[SEGP];
  int s = 0;
  #pragma unroll
  for (int j=0;j<SEGP;j++){ loc[j] = hist8[tid*SEGP + j]; s += loc[j]; }
  tsum[tid] = s;
  __syncthreads();
  for (int o=1;o<256;o<<=1){
    int t = (tid>=o) ? tsum[tid-o] : 0;
    __syncthreads();
    tsum[tid] += t;
    __syncthreads();
  }
  int run = tsum[tid] - s;  // exclusive across buckets
  #pragma unroll
  for (int j=0;j<SEGP;j++){ hcur8[tid*SEGP + j] = run; run += loc[j]; }
}

__global__ void k_perm(const int* __restrict__ degv, int* __restrict__ hcur8,
                       int* __restrict__ perm, int n){
  int gid = blockIdx.x*blockDim.x + threadIdx.x;
  if (gid < n){
    int d = degv[gid]; int b = d > 255 ? 255 : d;
    int pos = atomicAdd(&hcur8[b*SEGP + (gid>>14)], 1);
    if ((unsigned)pos < (unsigned)n) perm[pos] = gid;
  }
}

__global__ __launch_bounds__(256) void k_fill(const int* __restrict__ ei, int* __restrict__ cursor,
                                              int* __restrict__ csr, int E, int n){
  int g = blockIdx.x & (NGRP-1);
  int j = blockIdx.x >> 3;
  int span = (n + NGRP - 1) / NGRP;
  int lo = g * span;
  int base = j * CHUNK;
  if (base >= E) return;
  int end = base + CHUNK; if (end > E) end = E;
  for (int e = base + threadIdx.x; e < end; e += 256){
    int d = ei[E + e];
    if ((unsigned)(d - lo) < (unsigned)span && (unsigned)d < (unsigned)n){
      int s = ei[e];
      if ((unsigned)s < (unsigned)n){
        int pos = atomicAdd(&cursor[d], 1);
        if ((unsigned)pos < (unsigned)E) csr[pos] = s;
      }
    }
  }
}

// ---------------- proj_in: gather x[4] + (avg@A + x@B) + row softmax -> store p as fp8 (base 0) ----------------

__global__ __launch_bounds__(256) void k_in(const float* __restrict__ x, unsigned char* __restrict__ uout,
    const int* __restrict__ offs, const int* __restrict__ csr, const float* __restrict__ invdeg,
    const float* __restrict__ A, const float* __restrict__ B, int n){
  __shared__ float sA[128], sB[128];
  int tid = threadIdx.x;
  if (tid < 128){ sA[tid]=A[tid]; sB[tid]=B[tid]; }
  __syncthreads();
  int node = blockIdx.x*256 + tid;
  if (node >= n) return;
  float4 s = {0,0,0,0};
  int b0=offs[node], e0=offs[node+1];
  for (int k=b0;k<e0;k++){
    int sid = csr[k];
    float4 v = ((const float4*)x)[sid];
    s.x+=v.x; s.y+=v.y; s.z+=v.z; s.w+=v.w;
  }
  float idg = invdeg[node];
  s.x*=idg; s.y*=idg; s.z*=idg; s.w*=idg;
  float4 xr = ((const float4*)x)[node];
  float z[32];
  #pragma unroll
  for (int j=0;j<32;j++){
    z[j] = s.x*sA[j] + s.y*sA[32+j] + s.z*sA[64+j] + s.w*sA[96+j]
         + xr.x*sB[j] + xr.y*sB[32+j] + xr.z*sB[64+j] + xr.w*sB[96+j];
  }
  float m = z[0];
  #pragma unroll
  for (int j=1;j<32;j++) m = fmaxf(m,z[j]);
  float sum=0.0f;
  #pragma unroll
  for (int j=0;j<32;j++){ z[j]=expf(z[j]-m); sum+=z[j]; }
  float r = 1.0f/sum;
  unsigned pk[8];
  #pragma unroll
  for (int q=0;q<8;q++){
    int w0 = __builtin_amdgcn_cvt_pk_fp8_f32(z[4*q]*r,   z[4*q+1]*r, 0,  false);
    w0     = __builtin_amdgcn_cvt_pk_fp8_f32(z[4*q+2]*r, z[4*q+3]*r, w0, true);
    pk[q] = (unsigned)w0;
  }
  uint4* op = (uint4*)(uout + (size_t)node*32);
  op[0] = make_uint4(pk[0],pk[1],pk[2],pk[3]);
  op[1] = make_uint4(pk[4],pk[5],pk[6],pk[7]);
}

// ---------------- conv round (MFMA, fp8 state, degree-sorted order): wave = 16 nodes of
//  near-equal degree (perm) -> no ragged gather loops. Output rows scatter to original ids. ----------------

__global__ __launch_bounds__(256) void k_conv(
    const unsigned char* __restrict__ uin, unsigned char* __restrict__ uout,
    const int* __restrict__ offs, const int* __restrict__ csr,
    const float* __restrict__ invdeg, const int* __restrict__ perm,
    const float* __restrict__ Wa, const float* __restrict__ Wb,
    const float* __restrict__ cs_prev, float Rscale, float base,
    float* __restrict__ cs_next, int n){
  __shared__ float sWa[1024], sWb[1024];
  __shared__ float sCol[32];
  __shared__ unsigned char sU[64][32];
  __shared__ int sPid[64];
  int tid = threadIdx.x;
  float rcf = 1.0f;
  if (cs_prev) rcf = 131072.0f / ((float)n + cs_prev[(tid>>3)*CSTR]);  // rho = 2^17/colsum
  ((f4*)sWa)[tid] = ((const f4*)Wa)[tid] * rcf;
  ((f4*)sWb)[tid] = ((const f4*)Wb)[tid] * rcf;
  if (tid < 32) sCol[tid] = 0.0f;
  __syncthreads();

  int lane = tid & 63;
  int wv   = tid >> 6;
  int q    = lane >> 4;         // k-chunk (A) / row-quad (C)
  int c    = lane & 15;         // gather node (A's m) / output column (B's n, C's col)
  int tile = blockIdx.x*64 + wv*16;
  int idx  = tile + c;          // sorted index
  bool gv = idx < n;
  int pid = gv ? perm[idx] : -1;
  if (q == 0) sPid[wv*16 + c] = pid;

  // B-fragments in registers: B[k][n], k = q*8+j, n = c (lo) / c+16 (hi)
  h8 waLo, waHi, wbLo, wbHi;
  #pragma unroll
  for (int j=0;j<8;j++){
    int k = q*8 + j;
    waLo[j] = (_Float16)sWa[k*32 + c];
    waHi[j] = (_Float16)sWa[k*32 + c + 16];
    wbLo[j] = (_Float16)sWb[k*32 + c];
    wbHi[j] = (_Float16)sWb[k*32 + c + 16];
  }

  // gather: mean of neighbor v rows (fp8 decode), 8 plain loads in flight per lane
  f8 a0 = {0,0,0,0,0,0,0,0}, a1 = {0,0,0,0,0,0,0,0};
  f8 a2 = {0,0,0,0,0,0,0,0}, a3 = {0,0,0,0,0,0,0,0};
  int b0 = gv ? offs[pid]   : 0;
  int e0 = gv ? offs[pid+1] : 0;
  const uint2* ub = (const uint2*)uin;
  int k = b0;
  for (; k+8<=e0; k+=8){
    int s0=csr[k],   s1=csr[k+1], s2=csr[k+2], s3=csr[k+3];
    int s4=csr[k+4], s5=csr[k+5], s6=csr[k+6], s7=csr[k+7];
    uint2 v0 = ub[(size_t)s0*4 + q];
    uint2 v1 = ub[(size_t)s1*4 + q];
    uint2 v2 = ub[(size_t)s2*4 + q];
    uint2 v3 = ub[(size_t)s3*4 + q];
    uint2 v4 = ub[(size_t)s4*4 + q];
    uint2 v5 = ub[(size_t)s5*4 + q];
    uint2 v6 = ub[(size_t)s6*4 + q];
    uint2 v7 = ub[(size_t)s7*4 + q];
    a0 += dec8(v0); a1 += dec8(v1); a2 += dec8(v2); a3 += dec8(v3);
    a0 += dec8(v4); a1 += dec8(v5); a2 += dec8(v6); a3 += dec8(v7);
  }
  for (; k<e0; k++) a0 += dec8(ub[(size_t)csr[k]*4 + q]);
  a0 = (a0 + a1) + (a2 + a3);
  float idg = gv ? invdeg[pid] : 0.0f;
  float bavg = (idg != 0.0f) ? base : 0.0f;   // ref: isolated node -> avg = 0
  a0 = a0*idg + bavg;
  h8 afrag = __builtin_convertvector(a0, h8);
  f8 od = {0,0,0,0,0,0,0,0};
  if (gv) od = dec8(ub[(size_t)pid*4 + q]) + base;
  h8 ofrag = __builtin_convertvector(od, h8);

  f4 z1 = {0,0,0,0}, z2 = {0,0,0,0};
  z1 = __builtin_amdgcn_mfma_f32_16x16x32_f16(ofrag, wbLo, z1, 0, 0, 0);
  z1 = __builtin_amdgcn_mfma_f32_16x16x32_f16(afrag, waLo, z1, 0, 0, 0);
  z2 = __builtin_amdgcn_mfma_f32_16x16x32_f16(ofrag, wbHi, z2, 0, 0, 0);
  z2 = __builtin_amdgcn_mfma_f32_16x16x32_f16(afrag, waHi, z2, 0, 0, 0);
  z1 *= Rscale; z2 *= Rscale;

  // C layout: row (node-in-tile) = q*4 + r, col = c (z1) / c+16 (z2)
  f4 mx, sm;
  #pragma unroll
  for (int r=0;r<4;r++) mx[r] = fmaxf(z1[r], z2[r]);
  #pragma unroll
  for (int s=1;s<16;s<<=1){
    #pragma unroll
    for (int r=0;r<4;r++) mx[r] = fmaxf(mx[r], __shfl_xor(mx[r], s));
  }
  #pragma unroll
  for (int r=0;r<4;r++){
    z1[r] = expf(z1[r]-mx[r]);
    z2[r] = expf(z2[r]-mx[r]);
    sm[r] = z1[r] + z2[r];
  }
  #pragma unroll
  for (int s=1;s<16;s<<=1){
    #pragma unroll
    for (int r=0;r<4;r++) sm[r] += __shfl_xor(sm[r], s);
  }
  float cs1 = 0.0f, cs2 = 0.0f;
  #pragma unroll
  for (int r=0;r<4;r++){
    float rs = 1.0f/sm[r];
    float v1 = expf(z1[r]*rs) - 1.0f;   // store v = u - 1, v in [0, 1.72] (fp8-friendly)
    float v2 = expf(z2[r]*rs) - 1.0f;
    int p1 = __builtin_amdgcn_cvt_pk_fp8_f32(v1, v1, 0, false);
    int p2 = __builtin_amdgcn_cvt_pk_fp8_f32(v2, v2, 0, false);
    f2 d1 = __builtin_amdgcn_cvt_pk_f32_fp8(p1, false);
    f2 d2 = __builtin_amdgcn_cvt_pk_f32_fp8(p2, false);
    int lrow = wv*16 + q*4 + r;
    sU[lrow][c]      = (unsigned char)(p1 & 0xff);
    sU[lrow][c + 16] = (unsigned char)(p2 & 0xff);
    if (tile + q*4 + r < n){
      cs1 += d1[0];                 // colsum consistent with stored (rounded) v
      cs2 += d2[0];
    }
  }
  cs1 += __shfl_xor(cs1, 16); cs1 += __shfl_xor(cs1, 32);
  cs2 += __shfl_xor(cs2, 16); cs2 += __shfl_xor(cs2, 32);
  if (lane < 16){
    atomicAdd(&sCol[c],      cs1);
    atomicAdd(&sCol[c + 16], cs2);
  }
  __syncthreads();
  if (tid < 32) atomicAdd(&cs_next[tid*CSTR], sCol[tid]);
  // writeout: 8B/lane from LDS tile, scattered to original node ids
  int row = tid >> 2;
  int jj  = tid & 3;
  int pid2 = sPid[row];
  if (pid2 >= 0){
    uint2 val = *(const uint2*)&sU[row][jj*8];
    *(uint2*)(uout + (size_t)pid2*32 + jj*8) = val;
  }
}

// ---------------- output layer: z = (1+v)@ (W/colsum) + b = b + sum(ws) + v@ws ----------------

__global__ __launch_bounds__(256) void k_out1(const unsigned char* __restrict__ u, const float* __restrict__ W,
    const float* __restrict__ bptr, const float* __restrict__ cs_last,
    float* __restrict__ z, unsigned* __restrict__ zmaxkey, int n){
  __shared__ float ws[32];
  __shared__ float red[256];
  int tid = threadIdx.x;
  if (tid < 32) ws[tid] = W[tid] * (1.0f / ((float)n + cs_last[tid*CSTR]));
  __syncthreads();
  float sws = 0.0f;
  #pragma unroll
  for (int j=0;j<32;j++) sws += ws[j];
  int node = blockIdx.x*256 + tid;
  float zz = -3.0e38f;
  if (node < n){
    float acc = bptr[0] + sws;
    const uint4* ur = (const uint4*)(u + (size_t)node*32);
    uint4 w0 = ur[0], w1 = ur[1];
    unsigned wd[8] = {w0.x,w0.y,w0.z,w0.w,w1.x,w1.y,w1.z,w1.w};
    #pragma unroll
    for (int q=0;q<8;q++){
      f4 a = dec4(wd[q]);
      f4 w = ((const f4*)ws)[q];
      acc += a[0]*w[0] + a[1]*w[1] + a[2]*w[2] + a[3]*w[3];
    }
    z[node]=acc; zz=acc;
  }
  red[tid]=zz; __syncthreads();
  for (int s=128;s>0;s>>=1){
    if (tid<s) red[tid]=fmaxf(red[tid],red[tid+s]);
    __syncthreads();
  }
  if (tid==0) atomicMax(zmaxkey, f2key(red[0]));
}

__global__ __launch_bounds__(256) void k_out2(const float* __restrict__ z, const unsigned* __restrict__ zmaxkey,
                                              float* __restrict__ zsum, int n){
  __shared__ float red[256];
  int tid = threadIdx.x;
  int node = blockIdx.x*256 + tid;
  float zmax = key2f(*zmaxkey);
  float v = (node<n) ? expf(z[node]-zmax) : 0.0f;
  red[tid]=v; __syncthreads();
  for (int s=128;s>0;s>>=1){
    if (tid<s) red[tid]+=red[tid+s];
    __syncthreads();
  }
  if (tid==0) atomicAdd(zsum, red[0]);
}

__global__ __launch_bounds__(256) void k_out3(const float* __restrict__ z, const unsigned* __restrict__ zmaxkey,
                                              const float* __restrict__ zsum, float* __restrict__ out, int n){
  int node = blockIdx.x*256 + threadIdx.x;
  if (node < n){
    float zmax = key2f(*zmaxkey);
    out[node] = expf(z[node]-zmax) / (*zsum);
  }
}

// ---------------- host launcher ----------------

extern "C" void kernel_launch(void* const* d_in, const int* in_sizes, int n_in,
                              void* d_out, int out_size, void* d_ws, size_t ws_size,
                              hipStream_t stream) {
  const float* x      = (const float*)d_in[0];
  const int*   ei     = (const int*)d_in[1];   // int64 in reference -> int32 on device per harness
  const float* A_in   = (const float*)d_in[2];
  const float* B_in   = (const float*)d_in[3];
  const float* A_conv = (const float*)d_in[4];
  const float* B_conv = (const float*)d_in[5];
  const float* W_out  = (const float*)d_in[6];
  const float* b_out  = (const float*)d_in[7];
  const int N = in_sizes[0] / 4;
  const int E = in_sizes[1] / 2;
  const int NROUNDS = 16;

  char* w = (char*)d_ws;
  size_t o = 0;
  auto alloc = [&](size_t bytes)->char* {
    char* p = w + o;
    o = (o + bytes + 15) & ~(size_t)15;
    return p;
  };
  // ---- zero-init control region (one memset) ----
  int*      deg8    = (int*)     alloc((size_t)NSEG*N*4);
  int*      hist8   = (int*)     alloc((size_t)256*SEGP*4);
  float*    colsum  = (float*)   alloc((size_t)NROUNDS*32*CSTR*4);
  unsigned* zmaxkey = (unsigned*)alloc(4);
  float*    zsum    = (float*)   alloc(4);
  size_t ctrl_bytes = o;
  // ---- rest ----
  int*   offs    = (int*)  alloc((size_t)(N+1)*4);
  int*   cursor  = (int*)  alloc((size_t)N*4);
  float* invdeg  = (float*)alloc((size_t)N*4);
  int*   degv    = (int*)  alloc((size_t)N*4);
  int*   perm    = (int*)  alloc((size_t)N*4);
  int*   hcur8   = (int*)  alloc((size_t)256*SEGP*4);
  int    nb      = (N + 1023) / 1024;
  int*   bsum    = (int*)  alloc((size_t)nb*4);
  int*   bpre    = (int*)  alloc((size_t)nb*4);
  int*   csr     = (int*)  alloc((size_t)E*4);
  unsigned char* uA = (unsigned char*)alloc((size_t)N*32);
  unsigned char* uB = (unsigned char*)alloc((size_t)N*32);
  float* zbuf    = (float*)alloc((size_t)N*4);
  (void)ws_size; (void)n_in; (void)out_size;

  hipMemsetAsync(d_ws, 0, ctrl_bytes, stream);

  int gridN = (N + 255) / 256;
  int gridC = (N + 63) / 64;
  int bpg   = (E + CHUNK - 1) / CHUNK;

  // CSR build + degree sort
  k_deg  <<<NGRP*bpg, 256, 0, stream>>>(ei, deg8, E, N);
  k_scan1<<<nb, 1024, 0, stream>>>(deg8, offs, bsum, N);
  k_scan2<<<1, 64, 0, stream>>>(bsum, bpre, nb);
  k_scan3<<<gridN, 256, 0, stream>>>(offs, bpre, deg8, cursor, invdeg, degv, hist8, N, E);
  k_hscan<<<1, 256, 0, stream>>>(hist8, hcur8);
  k_perm <<<gridN, 256, 0, stream>>>(degv, hcur8, perm, N);
  k_fill <<<NGRP*bpg, 256, 0, stream>>>(ei, cursor, csr, E, N);

  // proj_in -> p stored fp8 (base 0)
  k_in<<<gridN, 256, 0, stream>>>(x, uA, offs, csr, invdeg, A_in, B_in, N);

  // 16 conv rounds (degree-sorted processing order)
  const float R17 = 1.0f/131072.0f;
  for (int r = 0; r < NROUNDS; r++){
    const float* Wa = A_conv + (size_t)r*32*32;
    const float* Wb = B_conv + (size_t)r*32*32;
    const float* cs_prev = (r == 0) ? nullptr : (colsum + (size_t)(r-1)*32*CSTR);
    float*       cs_next = colsum + (size_t)r*32*CSTR;
    float        Rs      = (r == 0) ? 1.0f : R17;
    float        base    = (r == 0) ? 0.0f : 1.0f;
    const unsigned char* ui = (r & 1) ? uB : uA;
    unsigned char*       uo = (r & 1) ? uA : uB;
    k_conv<<<gridC, 256, 0, stream>>>(ui, uo, offs, csr, invdeg, perm, Wa, Wb, cs_prev, Rs, base, cs_next, N);
  }

  // output layer (colsum_16 = n + sum(v); folded into W_out)
  k_out1<<<gridN, 256, 0, stream>>>(uA, W_out, b_out, colsum + (size_t)(NROUNDS-1)*32*CSTR, zbuf, zmaxkey, N);
  k_out2<<<gridN, 256, 0, stream>>>(zbuf, zmaxkey, zsum, N);
  k_out3<<<gridN, 256, 0, stream>>>(zbuf, zmaxkey, zsum, (float*)d_out, N);
}

// Round 13
// 1161.987 us; speedup vs baseline: 1.2772x; 1.2772x over previous
//
#include <hip/hip_runtime.h>

#define NSEG 8
#define SEGSH 19 // k_deg: segment = edge >> 19
#define NGRP 8   // k_fill: dst-range groups; group = blockIdx%8 -> fixed XCD
#define CHUNK 2048
#define CSTR 64  // colsum element stride (256B) -> spread across L2 slices

typedef float    f2 __attribute__((ext_vector_type(2)));
typedef float    f4 __attribute__((ext_vector_type(4)));
typedef float    f8 __attribute__((ext_vector_type(8)));
typedef _Float16 h8 __attribute__((ext_vector_type(8)));

__device__ __forceinline__ unsigned f2key(float x){
  unsigned b = __float_as_uint(x);
  return (b & 0x80000000u) ? ~b : (b | 0x80000000u);
}
__device__ __forceinline__ float key2f(unsigned k){
  return (k & 0x80000000u) ? __uint_as_float(k ^ 0x80000000u) : __uint_as_float(~k);
}

// fp8 e4m3 HW decode: 4 bytes -> 4 floats
__device__ __forceinline__ f4 dec4(unsigned w){
  f2 a = __builtin_amdgcn_cvt_pk_f32_fp8((int)w, false);
  f2 b = __builtin_amdgcn_cvt_pk_f32_fp8((int)w, true);
  f4 r; r[0]=a[0]; r[1]=a[1]; r[2]=b[0]; r[3]=b[1];
  return r;
}
__device__ __forceinline__ f8 dec8(uint2 w){
  f4 lo = dec4(w.x), hi = dec4(w.y);
  f8 r;
  r[0]=lo[0]; r[1]=lo[1]; r[2]=lo[2]; r[3]=lo[3];
  r[4]=hi[0]; r[5]=hi[1]; r[6]=hi[2]; r[7]=hi[3];
  return r;
}

// ---------------- CSR build (R6/R11 version — best measured; no nontemporal anywhere) ----------------

__global__ void k_deg(const int* __restrict__ ei, int* __restrict__ deg8, int E, int n){
  int e = blockIdx.x*blockDim.x + threadIdx.x;
  if (e < E){
    int d = ei[E + e];
    int seg = e >> SEGSH; if (seg > NSEG-1) seg = NSEG-1;
    if ((unsigned)d < (unsigned)n) atomicAdd(&deg8[seg*n + d], 1);
  }
}

__global__ __launch_bounds__(1024) void k_scan1(const int* __restrict__ deg8, int* __restrict__ offs,
                                                int* __restrict__ bsum, int n){
  __shared__ int tmp[1024];
  int tid = threadIdx.x;
  int gid = blockIdx.x*1024 + tid;
  int v = 0;
  if (gid < n){
    #pragma unroll
    for (int s=0;s<NSEG;s++) v += deg8[s*n + gid];
  }
  tmp[tid] = v;
  __syncthreads();
  for (int o=1;o<1024;o<<=1){
    int t = (tid>=o) ? tmp[tid-o] : 0;
    __syncthreads();
    if (tid>=o) tmp[tid] += t;
    __syncthreads();
  }
  int inc = tmp[tid];
  if (gid < n) offs[gid] = inc - v;   // exclusive within chunk
  if (tid == 1023) bsum[blockIdx.x] = inc;
}

__global__ void k_scan2(const int* __restrict__ bsum, int* __restrict__ bpre, int nb){
  if (threadIdx.x==0 && blockIdx.x==0){
    int acc=0;
    for (int i=0;i<nb;i++){ bpre[i]=acc; acc+=bsum[i]; }
  }
}

__global__ void k_scan3(int* __restrict__ offs, const int* __restrict__ bpre,
                        const int* __restrict__ deg8, int* __restrict__ cursor,
                        float* __restrict__ invdeg, int n, int E){
  int gid = blockIdx.x*blockDim.x + threadIdx.x;
  if (gid < n){
    int base = offs[gid] + bpre[gid>>10];
    offs[gid] = base;
    cursor[gid] = base;
    int dtot = 0;
    #pragma unroll
    for (int s=0;s<NSEG;s++) dtot += deg8[s*n + gid];
    invdeg[gid] = (dtot>0) ? 1.0f/(float)dtot : 0.0f;  // 0 marks isolated node (ref avg = 0)
  }
  if (gid==0) offs[n] = E;
}

__global__ __launch_bounds__(256) void k_fill(const int* __restrict__ ei, int* __restrict__ cursor,
                                              int* __restrict__ csr, int E, int n){
  int g = blockIdx.x & (NGRP-1);
  int j = blockIdx.x >> 3;
  int span = (n + NGRP - 1) / NGRP;
  int lo = g * span;
  int base = j * CHUNK;
  if (base >= E) return;
  int end = base + CHUNK; if (end > E) end = E;
  for (int e = base + threadIdx.x; e < end; e += 256){
    int d = ei[E + e];
    if ((unsigned)(d - lo) < (unsigned)span && (unsigned)d < (unsigned)n){
      int s = ei[e];
      if ((unsigned)s < (unsigned)n){
        int pos = atomicAdd(&cursor[d], 1);
        if ((unsigned)pos < (unsigned)E) csr[pos] = s;
      }
    }
  }
}

// ---------------- proj_in: gather x[4] + (avg@A + x@B) + row softmax -> store p as fp8 (base 0) ----------------

__global__ __launch_bounds__(256) void k_in(const float* __restrict__ x, unsigned char* __restrict__ uout,
    const int* __restrict__ offs, const int* __restrict__ csr, const float* __restrict__ invdeg,
    const float* __restrict__ A, const float* __restrict__ B, int n){
  __shared__ float sA[128], sB[128];
  int tid = threadIdx.x;
  if (tid < 128){ sA[tid]=A[tid]; sB[tid]=B[tid]; }
  __syncthreads();
  int node = blockIdx.x*256 + tid;
  if (node >= n) return;
  float4 s = {0,0,0,0};
  int b0=offs[node], e0=offs[node+1];
  for (int k=b0;k<e0;k++){
    int sid = csr[k];
    float4 v = ((const float4*)x)[sid];
    s.x+=v.x; s.y+=v.y; s.z+=v.z; s.w+=v.w;
  }
  float idg = invdeg[node];
  s.x*=idg; s.y*=idg; s.z*=idg; s.w*=idg;
  float4 xr = ((const float4*)x)[node];
  float z[32];
  #pragma unroll
  for (int j=0;j<32;j++){
    z[j] = s.x*sA[j] + s.y*sA[32+j] + s.z*sA[64+j] + s.w*sA[96+j]
         + xr.x*sB[j] + xr.y*sB[32+j] + xr.z*sB[64+j] + xr.w*sB[96+j];
  }
  float m = z[0];
  #pragma unroll
  for (int j=1;j<32;j++) m = fmaxf(m,z[j]);
  float sum=0.0f;
  #pragma unroll
  for (int j=0;j<32;j++){ z[j]=expf(z[j]-m); sum+=z[j]; }
  float r = 1.0f/sum;
  unsigned pk[8];
  #pragma unroll
  for (int q=0;q<8;q++){
    int w0 = __builtin_amdgcn_cvt_pk_fp8_f32(z[4*q]*r,   z[4*q+1]*r, 0,  false);
    w0     = __builtin_amdgcn_cvt_pk_fp8_f32(z[4*q+2]*r, z[4*q+3]*r, w0, true);
    pk[q] = (unsigned)w0;
  }
  uint4* op = (uint4*)(uout + (size_t)node*32);
  op[0] = make_uint4(pk[0],pk[1],pk[2],pk[3]);
  op[1] = make_uint4(pk[4],pk[5],pk[6],pk[7]);
}

// ---------------- conv round (MFMA, fp8 state): wave = 16 nodes. Plain loads. Output tile
//  staged in LDS -> coalesced 8B/lane stores. Structural floor: one random 32B row-request
//  per edge, throughput = E x L2-latency / (CUs x MSHRs) ~ 50us/round; invariant to payload
//  size (R6), cache placement (R9), and lane utilization (R12). ----------------

__global__ __launch_bounds__(256) void k_conv(
    const unsigned char* __restrict__ uin, unsigned char* __restrict__ uout,
    const int* __restrict__ offs, const int* __restrict__ csr,
    const float* __restrict__ invdeg,
    const float* __restrict__ Wa, const float* __restrict__ Wb,
    const float* __restrict__ cs_prev, float Rscale, float base,
    float* __restrict__ cs_next, int n){
  __shared__ float sWa[1024], sWb[1024];
  __shared__ float sCol[32];
  __shared__ unsigned char sU[64][32];
  int tid = threadIdx.x;
  float rcf = 1.0f;
  if (cs_prev) rcf = 131072.0f / ((float)n + cs_prev[(tid>>3)*CSTR]);  // rho = 2^17/colsum
  ((f4*)sWa)[tid] = ((const f4*)Wa)[tid] * rcf;
  ((f4*)sWb)[tid] = ((const f4*)Wb)[tid] * rcf;
  if (tid < 32) sCol[tid] = 0.0f;
  __syncthreads();

  int lane = tid & 63;
  int wv   = tid >> 6;
  int q    = lane >> 4;         // k-chunk (A) / row-quad (C)
  int c    = lane & 15;         // gather node (A's m) / output column (B's n, C's col)
  int tile = blockIdx.x*64 + wv*16;
  int node = tile + c;
  bool gv = node < n;

  // B-fragments in registers: B[k][n], k = q*8+j, n = c (lo) / c+16 (hi)
  h8 waLo, waHi, wbLo, wbHi;
  #pragma unroll
  for (int j=0;j<8;j++){
    int k = q*8 + j;
    waLo[j] = (_Float16)sWa[k*32 + c];
    waHi[j] = (_Float16)sWa[k*32 + c + 16];
    wbLo[j] = (_Float16)sWb[k*32 + c];
    wbHi[j] = (_Float16)sWb[k*32 + c + 16];
  }

  // gather: mean of neighbor v rows (fp8 decode), 8 plain loads in flight per lane
  f8 a0 = {0,0,0,0,0,0,0,0}, a1 = {0,0,0,0,0,0,0,0};
  f8 a2 = {0,0,0,0,0,0,0,0}, a3 = {0,0,0,0,0,0,0,0};
  int b0 = gv ? offs[node]   : 0;
  int e0 = gv ? offs[node+1] : 0;
  const uint2* ub = (const uint2*)uin;
  int k = b0;
  for (; k+8<=e0; k+=8){
    int s0=csr[k],   s1=csr[k+1], s2=csr[k+2], s3=csr[k+3];
    int s4=csr[k+4], s5=csr[k+5], s6=csr[k+6], s7=csr[k+7];
    uint2 v0 = ub[(size_t)s0*4 + q];
    uint2 v1 = ub[(size_t)s1*4 + q];
    uint2 v2 = ub[(size_t)s2*4 + q];
    uint2 v3 = ub[(size_t)s3*4 + q];
    uint2 v4 = ub[(size_t)s4*4 + q];
    uint2 v5 = ub[(size_t)s5*4 + q];
    uint2 v6 = ub[(size_t)s6*4 + q];
    uint2 v7 = ub[(size_t)s7*4 + q];
    a0 += dec8(v0); a1 += dec8(v1); a2 += dec8(v2); a3 += dec8(v3);
    a0 += dec8(v4); a1 += dec8(v5); a2 += dec8(v6); a3 += dec8(v7);
  }
  for (; k<e0; k++) a0 += dec8(ub[(size_t)csr[k]*4 + q]);
  a0 = (a0 + a1) + (a2 + a3);
  float idg = gv ? invdeg[node] : 0.0f;
  float bavg = (idg != 0.0f) ? base : 0.0f;   // ref: isolated node -> avg = 0
  a0 = a0*idg + bavg;
  h8 afrag = __builtin_convertvector(a0, h8);
  f8 od = {0,0,0,0,0,0,0,0};
  if (gv) od = dec8(ub[(size_t)node*4 + q]) + base;
  h8 ofrag = __builtin_convertvector(od, h8);

  f4 z1 = {0,0,0,0}, z2 = {0,0,0,0};
  z1 = __builtin_amdgcn_mfma_f32_16x16x32_f16(ofrag, wbLo, z1, 0, 0, 0);
  z1 = __builtin_amdgcn_mfma_f32_16x16x32_f16(afrag, waLo, z1, 0, 0, 0);
  z2 = __builtin_amdgcn_mfma_f32_16x16x32_f16(ofrag, wbHi, z2, 0, 0, 0);
  z2 = __builtin_amdgcn_mfma_f32_16x16x32_f16(afrag, waHi, z2, 0, 0, 0);
  z1 *= Rscale; z2 *= Rscale;

  // C layout: row (node-in-tile) = q*4 + r, col = c (z1) / c+16 (z2)
  f4 mx, sm;
  #pragma unroll
  for (int r=0;r<4;r++) mx[r] = fmaxf(z1[r], z2[r]);
  #pragma unroll
  for (int s=1;s<16;s<<=1){
    #pragma unroll
    for (int r=0;r<4;r++) mx[r] = fmaxf(mx[r], __shfl_xor(mx[r], s));
  }
  #pragma unroll
  for (int r=0;r<4;r++){
    z1[r] = expf(z1[r]-mx[r]);
    z2[r] = expf(z2[r]-mx[r]);
    sm[r] = z1[r] + z2[r];
  }
  #pragma unroll
  for (int s=1;s<16;s<<=1){
    #pragma unroll
    for (int r=0;r<4;r++) sm[r] += __shfl_xor(sm[r], s);
  }
  float cs1 = 0.0f, cs2 = 0.0f;
  #pragma unroll
  for (int r=0;r<4;r++){
    float rs = 1.0f/sm[r];
    float v1 = expf(z1[r]*rs) - 1.0f;   // store v = u - 1, v in [0, 1.72] (fp8-friendly)
    float v2 = expf(z2[r]*rs) - 1.0f;
    int p1 = __builtin_amdgcn_cvt_pk_fp8_f32(v1, v1, 0, false);
    int p2 = __builtin_amdgcn_cvt_pk_fp8_f32(v2, v2, 0, false);
    f2 d1 = __builtin_amdgcn_cvt_pk_f32_fp8(p1, false);
    f2 d2 = __builtin_amdgcn_cvt_pk_f32_fp8(p2, false);
    int lrow = wv*16 + q*4 + r;
    sU[lrow][c]      = (unsigned char)(p1 & 0xff);
    sU[lrow][c + 16] = (unsigned char)(p2 & 0xff);
    if (tile + q*4 + r < n){
      cs1 += d1[0];                 // colsum consistent with stored (rounded) v
      cs2 += d2[0];
    }
  }
  cs1 += __shfl_xor(cs1, 16); cs1 += __shfl_xor(cs1, 32);
  cs2 += __shfl_xor(cs2, 16); cs2 += __shfl_xor(cs2, 32);
  if (lane < 16){
    atomicAdd(&sCol[c],      cs1);
    atomicAdd(&sCol[c + 16], cs2);
  }
  __syncthreads();
  if (tid < 32) atomicAdd(&cs_next[tid*CSTR], sCol[tid]);
  // coalesced writeout: 8B/lane, tile staged in sU
  int row = tid >> 2;
  int jj  = tid & 3;
  int gnode = blockIdx.x*64 + row;
  if (gnode < n){
    uint2 val = *(const uint2*)&sU[row][jj*8];
    *(uint2*)(uout + (size_t)gnode*32 + jj*8) = val;
  }
}

// ---------------- output layer: z = (1+v)@ (W/colsum) + b = b + sum(ws) + v@ws ----------------

__global__ __launch_bounds__(256) void k_out1(const unsigned char* __restrict__ u, const float* __restrict__ W,
    const float* __restrict__ bptr, const float* __restrict__ cs_last,
    float* __restrict__ z, unsigned* __restrict__ zmaxkey, int n){
  __shared__ float ws[32];
  __shared__ float red[256];
  int tid = threadIdx.x;
  if (tid < 32) ws[tid] = W[tid] * (1.0f / ((float)n + cs_last[tid*CSTR]));
  __syncthreads();
  float sws = 0.0f;
  #pragma unroll
  for (int j=0;j<32;j++) sws += ws[j];
  int node = blockIdx.x*256 + tid;
  float zz = -3.0e38f;
  if (node < n){
    float acc = bptr[0] + sws;
    const uint4* ur = (const uint4*)(u + (size_t)node*32);
    uint4 w0 = ur[0], w1 = ur[1];
    unsigned wd[8] = {w0.x,w0.y,w0.z,w0.w,w1.x,w1.y,w1.z,w1.w};
    #pragma unroll
    for (int q=0;q<8;q++){
      f4 a = dec4(wd[q]);
      f4 w = ((const f4*)ws)[q];
      acc += a[0]*w[0] + a[1]*w[1] + a[2]*w[2] + a[3]*w[3];
    }
    z[node]=acc; zz=acc;
  }
  red[tid]=zz; __syncthreads();
  for (int s=128;s>0;s>>=1){
    if (tid<s) red[tid]=fmaxf(red[tid],red[tid+s]);
    __syncthreads();
  }
  if (tid==0) atomicMax(zmaxkey, f2key(red[0]));
}

__global__ __launch_bounds__(256) void k_out2(const float* __restrict__ z, const unsigned* __restrict__ zmaxkey,
                                              float* __restrict__ zsum, int n){
  __shared__ float red[256];
  int tid = threadIdx.x;
  int node = blockIdx.x*256 + tid;
  float zmax = key2f(*zmaxkey);
  float v = (node<n) ? expf(z[node]-zmax) : 0.0f;
  red[tid]=v; __syncthreads();
  for (int s=128;s>0;s>>=1){
    if (tid<s) red[tid]+=red[tid+s];
    __syncthreads();
  }
  if (tid==0) atomicAdd(zsum, red[0]);
}

__global__ __launch_bounds__(256) void k_out3(const float* __restrict__ z, const unsigned* __restrict__ zmaxkey,
                                              const float* __restrict__ zsum, float* __restrict__ out, int n){
  int node = blockIdx.x*256 + threadIdx.x;
  if (node < n){
    float zmax = key2f(*zmaxkey);
    out[node] = expf(z[node]-zmax) / (*zsum);
  }
}

// ---------------- host launcher ----------------

extern "C" void kernel_launch(void* const* d_in, const int* in_sizes, int n_in,
                              void* d_out, int out_size, void* d_ws, size_t ws_size,
                              hipStream_t stream) {
  const float* x      = (const float*)d_in[0];
  const int*   ei     = (const int*)d_in[1];   // int64 in reference -> int32 on device per harness
  const float* A_in   = (const float*)d_in[2];
  const float* B_in   = (const float*)d_in[3];
  const float* A_conv = (const float*)d_in[4];
  const float* B_conv = (const float*)d_in[5];
  const float* W_out  = (const float*)d_in[6];
  const float* b_out  = (const float*)d_in[7];
  const int N = in_sizes[0] / 4;
  const int E = in_sizes[1] / 2;
  const int NROUNDS = 16;

  char* w = (char*)d_ws;
  size_t o = 0;
  auto alloc = [&](size_t bytes)->char* {
    char* p = w + o;
    o = (o + bytes + 15) & ~(size_t)15;
    return p;
  };
  // ---- zero-init control region (one memset) ----
  int*      deg8    = (int*)     alloc((size_t)NSEG*N*4);
  float*    colsum  = (float*)   alloc((size_t)NROUNDS*32*CSTR*4);
  unsigned* zmaxkey = (unsigned*)alloc(4);
  float*    zsum    = (float*)   alloc(4);
  size_t ctrl_bytes = o;
  // ---- rest ----
  int*   offs    = (int*)  alloc((size_t)(N+1)*4);
  int*   cursor  = (int*)  alloc((size_t)N*4);
  float* invdeg  = (float*)alloc((size_t)N*4);
  int    nb      = (N + 1023) / 1024;
  int*   bsum    = (int*)  alloc((size_t)nb*4);
  int*   bpre    = (int*)  alloc((size_t)nb*4);
  int*   csr     = (int*)  alloc((size_t)E*4);
  unsigned char* uA = (unsigned char*)alloc((size_t)N*32);
  unsigned char* uB = (unsigned char*)alloc((size_t)N*32);
  float* zbuf    = (float*)alloc((size_t)N*4);
  (void)ws_size; (void)n_in; (void)out_size;

  hipMemsetAsync(d_ws, 0, ctrl_bytes, stream);

  int gridE = (E + 255) / 256;
  int gridN = (N + 255) / 256;
  int gridC = (N + 63) / 64;
  int bpg   = (E + CHUNK - 1) / CHUNK;

  // CSR build
  k_deg  <<<gridE, 256, 0, stream>>>(ei, deg8, E, N);
  k_scan1<<<nb, 1024, 0, stream>>>(deg8, offs, bsum, N);
  k_scan2<<<1, 64, 0, stream>>>(bsum, bpre, nb);
  k_scan3<<<gridN, 256, 0, stream>>>(offs, bpre, deg8, cursor, invdeg, N, E);
  k_fill <<<NGRP*bpg, 256, 0, stream>>>(ei, cursor, csr, E, N);

  // proj_in -> p stored fp8 (base 0)
  k_in<<<gridN, 256, 0, stream>>>(x, uA, offs, csr, invdeg, A_in, B_in, N);

  // 16 conv rounds
  const float R17 = 1.0f/131072.0f;
  for (int r = 0; r < NROUNDS; r++){
    const float* Wa = A_conv + (size_t)r*32*32;
    const float* Wb = B_conv + (size_t)r*32*32;
    const float* cs_prev = (r == 0) ? nullptr : (colsum + (size_t)(r-1)*32*CSTR);
    float*       cs_next = colsum + (size_t)r*32*CSTR;
    float        Rs      = (r == 0) ? 1.0f : R17;
    float        base    = (r == 0) ? 0.0f : 1.0f;
    const unsigned char* ui = (r & 1) ? uB : uA;
    unsigned char*       uo = (r & 1) ? uA : uB;
    k_conv<<<gridC, 256, 0, stream>>>(ui, uo, offs, csr, invdeg, Wa, Wb, cs_prev, Rs, base, cs_next, N);
  }

  // output layer (colsum_16 = n + sum(v); folded into W_out)
  k_out1<<<gridN, 256, 0, stream>>>(uA, W_out, b_out, colsum + (size_t)(NROUNDS-1)*32*CSTR, zbuf, zmaxkey, N);
  k_out2<<<gridN, 256, 0, stream>>>(zbuf, zmaxkey, zsum, N);
  k_out3<<<gridN, 256, 0, stream>>>(zbuf, zmaxkey, zsum, (float*)d_out, N);
}